// Round 5
// baseline (205.487 us; speedup 1.0000x reference)
//
#include <hip/hip_runtime.h>

// TimeConcater: new_x[b,p,d] = sum_l [bucket(ts[b,l])==p] * x[b,l,d]
// B=32, L=4096, D=256, P=32 buckets over np.linspace(0,1.001,33) edges.
// Output flat: new_x (32,32,256), then time_steps (32,4096).
//
// R14: global_load_lds + FREE-RUNNING per-wave ring (the untested quadrant).
// Evidence: R8 (gather/NT/VGPR, 24w) ~35us, R10 (stripe/NT/VGPR) ~39us,
// R13 (seq/NT/VGPR, 16w) ~36us -- three access patterns converge at
// 3.7-4.2 TB/s => per-CU cap on the VGPR-returning load path, pattern-
// and occupancy-independent. R11 proved nothing about the lds-direct path
// (barrier-lockstep exposed 12K cyc/chunk). Here:
//  - wave w owns rows i*8+w; stages whole 1KB rows into a PRIVATE 8-slot
//    LDS ring via width-16 global_load_lds (no VGPR round-trip);
//  - vmcnt is per-wave state -> counted s_waitcnt vmcnt(7) paces each
//    wave's own ring; ZERO barriers in the main loop (R11's lesson);
//  - ds_read_b128 slot -> quantize (S=2^16) -> 4 ds_add_u32 into the
//    shared SoA int accumulator (R13's mechanism; bank = lane&31, free);
//  - slot-reuse hazard: ds_read data is forced into regs (lgkmcnt wait
//    before cvt) and atomics precede the re-stage via a "memory" clobber,
//    so the overwriting DMA (>=900cy away) can't beat the read (~120cy).
//  - NSEG=8 (512 rows/block, 256 blocks = 1/CU): epilogue global-atomic
//    merge halved vs R13 (2.1M adds).
// Decision value: win (~179-182us) => lds path escapes the cap;
// neutral (>=188) => cap is path-universal, ~36us is this op's floor.

#define Bk 32
#define Lk 4096
#define Dk 256
#define Pk 32
#define NSEG 8
#define RB (Lk / NSEG)       // 512 rows per block
#define NTH 512              // 8 waves
#define NW 8
#define RING 8               // ring slots (rows) per wave, 8 KB
#define RPW (RB / NW)        // 64 rows per wave

typedef float v4f __attribute__((ext_vector_type(4)));
typedef const __attribute__((address_space(1))) void* gas_t;
typedef __attribute__((address_space(3))) void* las_t;

__device__ __forceinline__ int bucket_of(float tv) {
    // Emulate np.linspace(0.0, 1.001, 33): edge(i) = float32((double)i * (1.001/32))
    const double step = 1.001 / 32.0;
    int p = (int)(tv * (float)(32.0 / 1.001));
    p = p < 0 ? 0 : (p > 31 ? 31 : p);
    while (p > 0 && tv < (float)((double)p * step)) --p;
    while (p < 31 && tv >= (float)((double)(p + 1) * step)) ++p;
    return p;
}

__global__ __launch_bounds__(NTH, 1) void tc_ring(
        const float* __restrict__ x,
        const float* __restrict__ ts,
        float* __restrict__ out,
        float* __restrict__ ts_out) {
    __shared__ float ring[NW][RING][Dk];      // 64 KB: wave-private rings
    __shared__ int acc[4 * Pk * 64];          // 32 KB shared SoA accumulator
    __shared__ unsigned char pbuf[RB];        // 512 B buckets

    const int seg  = blockIdx.x;
    const int b    = blockIdx.y;
    const int t    = threadIdx.x;
    const int w    = t >> 6;
    const int lane = t & 63;

    // Zero acc (2048 v4f / 512 thr = 4 each).
    {
        v4f z = 0.f;
#pragma unroll
        for (int i = t; i < 4 * Pk * 64 / 4; i += NTH) ((v4f*)acc)[i] = z;
    }

    // Buckets + ts passthrough: exactly one row per thread (RB == NTH).
    {
        const size_t li = (size_t)b * Lk + (size_t)seg * RB + t;
        const float tv = ts[li];
        ts_out[li] = tv;
        pbuf[t] = (unsigned char)bucket_of(tv);
    }
    __syncthreads();    // only block-wide sync; main loop is barrier-free

    const float* xb = x + ((size_t)b * Lk + (size_t)seg * RB) * Dk;

    // Stage row (i*NW + w) into ring[w][slot]: per-lane GLOBAL address,
    // wave-UNIFORM LDS base (HW writes lane*16 linear -- m104/m108).
    auto stage = [&](int i, int slot) {
        const int r = i * NW + w;
        const float* g = xb + (size_t)r * Dk + (lane << 2);
        __builtin_amdgcn_global_load_lds((gas_t)g, (las_t)&ring[w][slot][0],
                                         16, 0, 0);
    };

#pragma unroll
    for (int s = 0; s < RING; ++s) stage(s, s);

    const float S = 65536.0f;
    for (int i = 0; i < RPW; ++i) {
        const int slot = i & (RING - 1);
        // Pace on MY loads only (vmcnt is per-wave): keep 7 in flight.
        if (i < RPW - RING)       asm volatile("s_waitcnt vmcnt(7)" ::: "memory");
        else if (i == RPW - RING) asm volatile("s_waitcnt vmcnt(0)" ::: "memory");

        const int p = pbuf[i * NW + w];                       // u8 broadcast
        const v4f v = *(const v4f*)&ring[w][slot][lane << 2]; // ds_read_b128
        const int base = (p << 6) + lane;                     // bank=lane&31
        atomicAdd(&acc[base       ], __float2int_rn(v.x * S));
        atomicAdd(&acc[base + 2048], __float2int_rn(v.y * S));
        atomicAdd(&acc[base + 4096], __float2int_rn(v.z * S));
        atomicAdd(&acc[base + 6144], __float2int_rn(v.w * S));
        asm volatile("" ::: "memory");   // atomics (mem ops) precede re-stage
        if (i + RING < RPW) stage(i + RING, slot);
    }
    __syncthreads();    // drains lgkmcnt: all ds_add complete

    // K-split merge (2.1M global f32 atomics total) onto memset-zeroed out.
    const float IS = 1.0f / 65536.0f;
    float* ob = out + (size_t)b * Pk * Dk;
#pragma unroll
    for (int e = t; e < Pk * Dk; e += NTH) {
        const int p = e >> 8;
        const int c = e & 255;
        const int iv = acc[((c & 3) << 11) + (p << 6) + (c >> 2)];
        unsafeAtomicAdd(ob + e, (float)iv * IS);
    }
}

extern "C" void kernel_launch(void* const* d_in, const int* in_sizes, int n_in,
                              void* d_out, int out_size, void* d_ws, size_t ws_size,
                              hipStream_t stream) {
    const float* x  = (const float*)d_in[0];
    const float* ts = (const float*)d_in[1];
    float* out = (float*)d_out;
    float* ts_out = out + (size_t)Bk * Pk * Dk;

    hipMemsetAsync(out, 0, (size_t)Bk * Pk * Dk * sizeof(float), stream);
    dim3 grid(NSEG, Bk);   // 256 blocks = 1/CU, 8 free-running waves each
    tc_ring<<<grid, NTH, 0, stream>>>(x, ts, out, ts_out);
}

// Round 7
// 193.914 us; speedup vs baseline: 1.0597x; 1.0597x over previous
//
#include <hip/hip_runtime.h>

// TimeConcater: new_x[b,p,d] = sum_l [bucket(ts[b,l])==p] * x[b,l,d]
// B=32, L=4096, D=256, P=32 buckets over np.linspace(0,1.001,33) edges.
// Output flat: new_x (32,32,256), then time_steps (32,4096).
//
// R15 (resubmit; R6's bench run died in the harness: "container failed
// twice" — no compile/test signal, so the A/B below is still unrun).
// R15: R13 with PLAIN (temporal) loads — single-variable A/B.
// Evidence audit: every 3.7-4.2 TB/s variant (R8 gather, R10 stripe, R13
// seq stream) used __builtin_nontemporal_load; the known-good 6.29 TB/s
// copy (m13) and 6.9 TB/s fillBuffer use temporal accesses. Theory: the
// nt bit bypasses L1 line allocation -> a 1KB dwordx4 wave-instr becomes
// 64 separate 16B sector requests to L2 (8x request count) -> per-CU
// L2-request-rate cap ~6 B/cyc = 3.7 TB/s chip-wide. Explains pattern-
// independence (all NT), occupancy-independence (request path saturates
// with few waves), and writes being 4.5x faster through the same TA.
// NT was right for R8's SCATTERED gather (L1-miss pileup), wrong for a
// sequential stream. R14 (lds-direct ring, 52us) already falsified the
// "escape via global_load_lds" branch.
// Everything else identical to R13 (best-known stream): 512 blocks (2/CU,
// free-running), 1 wave-instr = 1 row, fixed-point ds_add_u32 into shared
// SoA acc (bank=lane&31, 2/bank free), K-split merge via global f32
// atomics onto memset-zeroed out. S=2^16 (perf-neutral; absmax ~0.125).
// Decision rule: dur >=187 => cap is NT-independent => declare roofline.

#define Bk 32
#define Lk 4096
#define Dk 256
#define Pk 32
#define NRS 16
#define RB (Lk / NRS)        // 256 rows per block
#define NTH 512              // 8 waves
#define NW 8
#define UN 8                 // load unroll depth (8 KB in flight per wave)

typedef float v4f __attribute__((ext_vector_type(4)));

__device__ __forceinline__ int bucket_of(float tv) {
    // Emulate np.linspace(0.0, 1.001, 33): edge(i) = float32((double)i * (1.001/32))
    const double step = 1.001 / 32.0;
    int p = (int)(tv * (float)(32.0 / 1.001));
    p = p < 0 ? 0 : (p > 31 ? 31 : p);
    while (p > 0 && tv < (float)((double)p * step)) --p;
    while (p < 31 && tv >= (float)((double)(p + 1) * step)) ++p;
    return p;
}

__global__ __launch_bounds__(NTH, 4) void tc_fx2(
        const float* __restrict__ x,
        const float* __restrict__ ts,
        float* __restrict__ out,
        float* __restrict__ ts_out) {
    // SoA int accumulator: plane j (=col&3) at [p][c>>2]. Atomic addr
    // dwords = j*2048 + p*64 + lane -> per-instr bank = lane&31 (2/bank,
    // free) regardless of p. Shared by ALL waves: atomics need no privacy.
    __shared__ int acc[4 * Pk * 64];          // 32 KB
    __shared__ unsigned char pbuf[RB];        // 256 B

    const int rs = blockIdx.x;
    const int b  = blockIdx.y;
    const int t  = threadIdx.x;
    const int w  = t >> 6;
    const int lane = t & 63;

    // Zero acc (2048 v4f / 512 thr = 4 each).
    {
        v4f z = 0.f;
#pragma unroll
        for (int i = t; i < 4 * Pk * 64 / 4; i += NTH) ((v4f*)acc)[i] = z;
    }

    // Buckets + ts passthrough for this block's 256 rows.
    if (t < RB) {
        const size_t li = (size_t)b * Lk + (size_t)rs * RB + t;
        const float tv = ts[li];
        ts_out[li] = tv;
        pbuf[t] = (unsigned char)bucket_of(tv);
    }
    __syncthreads();

    // Free-running stream: iteration (i0+u), wave w reads row (i0+u)*8+w
    // -> the block's in-flight window is 64 KB of CONTIGUOUS rows.
    // PLAIN dwordx4 loads: L1 line-fill coalescing (8x128B per wave-instr)
    // instead of NT's per-lane sector requests.
    const float* xb = x + ((size_t)b * Lk + (size_t)rs * RB) * Dk + (lane << 2);
    const float S = 65536.0f;

    for (int i0 = 0; i0 < RB / NW; i0 += UN) {
        v4f v[UN];
        int pu[UN];
#pragma unroll
        for (int u = 0; u < UN; ++u) {
            const int r = (i0 + u) * NW + w;
            v[u] = *(const v4f*)(xb + (size_t)r * Dk);   // temporal
            pu[u] = pbuf[r];                  // ds_read_u8 broadcast
        }
#pragma unroll
        for (int u = 0; u < UN; ++u) {
            const int base = (pu[u] << 6) + lane;
            atomicAdd(&acc[base       ], __float2int_rn(v[u].x * S));
            atomicAdd(&acc[base + 2048], __float2int_rn(v[u].y * S));
            atomicAdd(&acc[base + 4096], __float2int_rn(v[u].z * S));
            atomicAdd(&acc[base + 6144], __float2int_rn(v[u].w * S));
        }
    }
    __syncthreads();

    // Merge this K-segment's partial into out (zeroed by memset):
    // 8192 cells / 512 thr = 16 global f32 atomics each, coalesced.
    const float IS = 1.0f / 65536.0f;
    float* ob = out + (size_t)b * Pk * Dk;
#pragma unroll
    for (int e = t; e < Pk * Dk; e += NTH) {
        const int p = e >> 8;
        const int c = e & 255;
        const int iv = acc[((c & 3) << 11) + (p << 6) + (c >> 2)];
        unsafeAtomicAdd(ob + e, (float)iv * IS);
    }
}

extern "C" void kernel_launch(void* const* d_in, const int* in_sizes, int n_in,
                              void* d_out, int out_size, void* d_ws, size_t ws_size,
                              hipStream_t stream) {
    const float* x  = (const float*)d_in[0];
    const float* ts = (const float*)d_in[1];
    float* out = (float*)d_out;
    float* ts_out = out + (size_t)Bk * Pk * Dk;

    hipMemsetAsync(out, 0, (size_t)Bk * Pk * Dk * sizeof(float), stream);
    dim3 grid(NRS, Bk);   // 512 blocks = 2 per CU, free-running
    tc_fx2<<<grid, NTH, 0, stream>>>(x, ts, out, ts_out);
}